// Round 1
// baseline (48.360 us; speedup 1.0000x reference)
//
#include <hip/hip_runtime.h>

#define H 512
#define W 512
#define C 3
#define HW (H * W)

// Each thread computes 4 consecutive x outputs for one (n, y) row.
// Block: (64, 4) = 256 threads. Grid: (W/256, H/4, N) = (2, 128, 32).
__global__ __launch_bounds__(256) void sobel_kernel(const float* __restrict__ img,
                                                    float* __restrict__ out) {
    const int tx = threadIdx.x;                  // 0..63
    const int ty = threadIdx.y;                  // 0..3
    const int x0 = (blockIdx.x * 64 + tx) * 4;   // multiple of 4
    const int y  = blockIdx.y * 4 + ty;
    const int n  = blockIdx.z;

    // Edge-pad semantics == clamp the stencil center into [1, 510].
    const int yc = min(max(y, 1), H - 2);

    const float* base = img + (size_t)n * C * HW;

    // 6-column window covers cols x0-1 .. x0+4; clamp the two edge taps so we
    // never read out of bounds (their results get overwritten at x edges).
    const int lcol = max(x0 - 1, 0);
    const int rcol = min(x0 + 4, W - 1);

    float w[3][6];
#pragma unroll
    for (int r = 0; r < 3; ++r) {
        const int row = yc - 1 + r;
        float l = 0.f, rr = 0.f;
        float4 v = make_float4(0.f, 0.f, 0.f, 0.f);
#pragma unroll
        for (int c = 0; c < C; ++c) {
            const float* p = base + (size_t)c * HW + (size_t)row * W;
            l += p[lcol];
            rr += p[rcol];
            const float4 t = *reinterpret_cast<const float4*>(p + x0);
            v.x += t.x; v.y += t.y; v.z += t.z; v.w += t.w;
        }
        w[r][0] = l;
        w[r][1] = v.x; w[r][2] = v.y; w[r][3] = v.z; w[r][4] = v.w;
        w[r][5] = rr;
    }

    float res[4];
#pragma unroll
    for (int k = 0; k < 4; ++k) {
        // Gx: col weights [1,0,-1] x row weights [1,2,1]
        const float gx = (w[0][k] - w[0][k + 2])
                       + 2.f * (w[1][k] - w[1][k + 2])
                       + (w[2][k] - w[2][k + 2]);
        // Gy: row(yc-1) weights [1,2,1] minus row(yc+1) weights [1,2,1]
        const float gy = (w[0][k] + 2.f * w[0][k + 1] + w[0][k + 2])
                       - (w[2][k] + 2.f * w[2][k + 1] + w[2][k + 2]);
        res[k] = sqrtf(gx * gx + gy * gy);
    }

    // x edge-pad fixups: out(x=0) = out(x=1), out(x=511) = out(x=510)
    if (x0 == 0)     res[0] = res[1];
    if (x0 == W - 4) res[3] = res[2];

    float4* o = reinterpret_cast<float4*>(out + (size_t)n * HW + (size_t)y * W + x0);
    *o = make_float4(res[0], res[1], res[2], res[3]);
}

extern "C" void kernel_launch(void* const* d_in, const int* in_sizes, int n_in,
                              void* d_out, int out_size, void* d_ws, size_t ws_size,
                              hipStream_t stream) {
    const float* img = (const float*)d_in[0];
    float* out = (float*)d_out;

    dim3 block(64, 4, 1);
    dim3 grid(W / (64 * 4), H / 4, 32);
    sobel_kernel<<<grid, block, 0, stream>>>(img, out);
}

// Round 2
// 35.802 us; speedup vs baseline: 1.3507x; 1.3507x over previous
//
#include <hip/hip_runtime.h>

#define H 512
#define W 512
#define C 3
#define HW (H * W)

// 4x4 output tile per thread. Block (64,4): each wave (ty) owns a 256-px row
// segment x [blockIdx.x*256, +256) and 4 output rows. Grid (2, 32, 32).
__global__ __launch_bounds__(256) void sobel_kernel(const float* __restrict__ img,
                                                    float* __restrict__ out) {
    const int tx = threadIdx.x;                      // 0..63 (lane)
    const int ty = threadIdx.y;                      // 0..3  (wave)
    const int x0 = blockIdx.x * 256 + tx * 4;        // multiple of 4
    const int y0 = (blockIdx.y * 4 + ty) * 4;        // multiple of 4
    const int n  = blockIdx.z;

    const float* p0 = img + (size_t)n * C * HW;
    const float* p1 = p0 + HW;
    const float* p2 = p0 + 2 * HW;

    // Block-boundary halo column (only lanes 0 and 63 need a real load).
    const int  ecol  = (tx == 0) ? (x0 - 1) : (x0 + 4);
    const bool eneed = (tx == 0 && x0 > 0) || (tx == 63 && x0 + 4 < W);

    float gx[4][4];
    float gy[4][4];

#pragma unroll
    for (int j = 0; j < 6; ++j) {
        int row = y0 - 1 + j;
        row = min(max(row, 0), H - 1);
        const size_t ro = (size_t)row * W;

        const float4 a = *reinterpret_cast<const float4*>(p0 + ro + x0);
        const float4 b = *reinterpret_cast<const float4*>(p1 + ro + x0);
        const float4 c = *reinterpret_cast<const float4*>(p2 + ro + x0);
        const float s0 = a.x + b.x + c.x;
        const float s1 = a.y + b.y + c.y;
        const float s2 = a.z + b.z + c.z;
        const float s3 = a.w + b.w + c.w;

        float edge = 0.f;
        if (eneed) edge = p0[ro + ecol] + p1[ro + ecol] + p2[ro + ecol];

        float left = __shfl_up(s3, 1);
        if (tx == 0) left = edge;          // garbage when x0==0; result discarded
        float right = __shfl_down(s0, 1);
        if (tx == 63) right = edge;        // garbage when x0+4==W; result discarded

        const float win[6] = {left, s0, s1, s2, s3, right};

        float cd[4], cs[4];
#pragma unroll
        for (int m = 0; m < 4; ++m) {
            cd[m] = win[m] - win[m + 2];                       // Gx col weights [1,0,-1]
            cs[m] = win[m] + 2.f * win[m + 1] + win[m + 2];    // Gy col weights [1,2,1]
        }

        // Output row k (center row j=k+1) uses loaded rows k, k+1, k+2:
        //   gx[k] = cd[k] + 2*cd[k+1] + cd[k+2];  gy[k] = cs[k] - cs[k+2]
#pragma unroll
        for (int m = 0; m < 4; ++m) {
            if (j < 4)             { gx[j][m] = cd[m];       gy[j][m] = cs[m]; }
            if (j >= 1 && j <= 4)  { gx[j - 1][m] += 2.f * cd[m]; }
            if (j >= 2)            { gx[j - 2][m] += cd[m];  gy[j - 2][m] -= cs[m]; }
        }
    }

    float res[4][4];
#pragma unroll
    for (int k = 0; k < 4; ++k)
#pragma unroll
        for (int m = 0; m < 4; ++m)
            res[k][m] = sqrtf(gx[k][m] * gx[k][m] + gy[k][m] * gy[k][m]);

    // Edge-pad fixups (result duplication). x first, then y (y copies fixed rows).
    if (x0 == 0) {
#pragma unroll
        for (int k = 0; k < 4; ++k) res[k][0] = res[k][1];
    }
    if (x0 == W - 4) {
#pragma unroll
        for (int k = 0; k < 4; ++k) res[k][3] = res[k][2];
    }
    if (y0 == 0) {
#pragma unroll
        for (int m = 0; m < 4; ++m) res[0][m] = res[1][m];
    }
    if (y0 == H - 4) {
#pragma unroll
        for (int m = 0; m < 4; ++m) res[3][m] = res[2][m];
    }

    float* o = out + (size_t)n * HW + (size_t)y0 * W + x0;
#pragma unroll
    for (int k = 0; k < 4; ++k)
        *reinterpret_cast<float4*>(o + (size_t)k * W) =
            make_float4(res[k][0], res[k][1], res[k][2], res[k][3]);
}

extern "C" void kernel_launch(void* const* d_in, const int* in_sizes, int n_in,
                              void* d_out, int out_size, void* d_ws, size_t ws_size,
                              hipStream_t stream) {
    const float* img = (const float*)d_in[0];
    float* out = (float*)d_out;

    dim3 block(64, 4, 1);
    dim3 grid(W / 256, H / 16, 32);
    sobel_kernel<<<grid, block, 0, stream>>>(img, out);
}

// Round 4
// 29.173 us; speedup vs baseline: 1.6577x; 1.2272x over previous
//
#include <hip/hip_runtime.h>

#define H 512
#define W 512
#define C 3
#define HW (H * W)

typedef float f32x4 __attribute__((ext_vector_type(4)));

// 4x4 output tile per thread. Block (64,4): each wave (ty) owns a 256-px row
// segment and 4 output rows. Grid (2, 32, 32).
// All 18 stencil loads are hoisted into registers up-front so they are all
// in flight simultaneously (round-1 version had VGPR=44 -> serialized loads).
__global__ __launch_bounds__(256) void sobel_kernel(const float* __restrict__ img,
                                                    float* __restrict__ out) {
    const int tx = threadIdx.x;                      // 0..63 (lane)
    const int ty = threadIdx.y;                      // 0..3  (wave)
    const int x0 = blockIdx.x * 256 + tx * 4;        // multiple of 4
    const int y0 = (blockIdx.y * 4 + ty) * 4;        // multiple of 4
    const int n  = blockIdx.z;

    const float* p0 = img + (size_t)n * C * HW;
    const float* p1 = p0 + HW;
    const float* p2 = p0 + 2 * HW;

    // Row offsets (edge-pad == clamp center into [1,510] == clamp loaded rows).
    size_t ro[6];
#pragma unroll
    for (int j = 0; j < 6; ++j) {
        int row = y0 - 1 + j;
        row = min(max(row, 0), H - 1);
        ro[j] = (size_t)row * W;
    }

    // ---- prologue: issue ALL vector loads back-to-back ----
    f32x4 A[6][3];
#pragma unroll
    for (int j = 0; j < 6; ++j) {
        A[j][0] = *reinterpret_cast<const f32x4*>(p0 + ro[j] + x0);
        A[j][1] = *reinterpret_cast<const f32x4*>(p1 + ro[j] + x0);
        A[j][2] = *reinterpret_cast<const f32x4*>(p2 + ro[j] + x0);
    }

    // Block-boundary halo column (only lanes 0 and 63 load; exec has at most
    // 2 active lanes here, 18 cheap scalar loads).
    const int  ecol  = (tx == 0) ? (x0 - 1) : (x0 + 4);
    const bool eneed = (tx == 0 && x0 > 0) || (tx == 63 && x0 + 4 < W);
    float e[6] = {0.f, 0.f, 0.f, 0.f, 0.f, 0.f};
    if (eneed) {
#pragma unroll
        for (int j = 0; j < 6; ++j)
            e[j] = p0[ro[j] + ecol] + p1[ro[j] + ecol] + p2[ro[j] + ecol];
    }

    float gx[4][4];
    float gy[4][4];

#pragma unroll
    for (int j = 0; j < 6; ++j) {
        const float s0 = A[j][0].x + A[j][1].x + A[j][2].x;
        const float s1 = A[j][0].y + A[j][1].y + A[j][2].y;
        const float s2 = A[j][0].z + A[j][1].z + A[j][2].z;
        const float s3 = A[j][0].w + A[j][1].w + A[j][2].w;

        float left = __shfl_up(s3, 1);
        if (tx == 0) left = e[j];          // garbage when x0==0; result discarded
        float right = __shfl_down(s0, 1);
        if (tx == 63) right = e[j];        // garbage when x0+4==W; result discarded

        const float win[6] = {left, s0, s1, s2, s3, right};

        float cd[4], cs[4];
#pragma unroll
        for (int m = 0; m < 4; ++m) {
            cd[m] = win[m] - win[m + 2];                       // Gx col weights [1,0,-1]
            cs[m] = win[m] + 2.f * win[m + 1] + win[m + 2];    // Gy col weights [1,2,1]
        }

        // Output row k (center row j=k+1) uses loaded rows k, k+1, k+2:
        //   gx[k] = cd[k] + 2*cd[k+1] + cd[k+2];  gy[k] = cs[k] - cs[k+2]
#pragma unroll
        for (int m = 0; m < 4; ++m) {
            if (j < 4)             { gx[j][m] = cd[m];       gy[j][m] = cs[m]; }
            if (j >= 1 && j <= 4)  { gx[j - 1][m] += 2.f * cd[m]; }
            if (j >= 2)            { gx[j - 2][m] += cd[m];  gy[j - 2][m] -= cs[m]; }
        }
    }

    float res[4][4];
#pragma unroll
    for (int k = 0; k < 4; ++k)
#pragma unroll
        for (int m = 0; m < 4; ++m)
            res[k][m] = sqrtf(gx[k][m] * gx[k][m] + gy[k][m] * gy[k][m]);

    // Edge-pad fixups (result duplication). x first, then y (y copies fixed rows).
    if (x0 == 0) {
#pragma unroll
        for (int k = 0; k < 4; ++k) res[k][0] = res[k][1];
    }
    if (x0 == W - 4) {
#pragma unroll
        for (int k = 0; k < 4; ++k) res[k][3] = res[k][2];
    }
    if (y0 == 0) {
#pragma unroll
        for (int m = 0; m < 4; ++m) res[0][m] = res[1][m];
    }
    if (y0 == H - 4) {
#pragma unroll
        for (int m = 0; m < 4; ++m) res[3][m] = res[2][m];
    }

    // Streaming (non-temporal) stores: output is never re-read; keep L2 for img.
    float* o = out + (size_t)n * HW + (size_t)y0 * W + x0;
#pragma unroll
    for (int k = 0; k < 4; ++k) {
        f32x4 v = {res[k][0], res[k][1], res[k][2], res[k][3]};
        __builtin_nontemporal_store(v, reinterpret_cast<f32x4*>(o + (size_t)k * W));
    }
}

extern "C" void kernel_launch(void* const* d_in, const int* in_sizes, int n_in,
                              void* d_out, int out_size, void* d_ws, size_t ws_size,
                              hipStream_t stream) {
    const float* img = (const float*)d_in[0];
    float* out = (float*)d_out;

    dim3 block(64, 4, 1);
    dim3 grid(W / 256, H / 16, 32);
    sobel_kernel<<<grid, block, 0, stream>>>(img, out);
}

// Round 5
// 25.172 us; speedup vs baseline: 1.9212x; 1.1590x over previous
//
#include <hip/hip_runtime.h>

#define H 512
#define W 512
#define C 3
#define HW (H * W)

typedef float f32x4 __attribute__((ext_vector_type(4)));

// 4x4 output tile per thread. Block (64,4): each block covers a 256-px x
// segment and 16 y rows. 1D grid of 2048 blocks, XCD-chunked swizzle:
// each of the 8 XCDs owns 4 complete images (256 consecutive blocks), so
// y-adjacent blocks (sharing halo rows / streaming neighbors) stay on the
// same XCD's 4 MB L2 instead of bouncing through L3.
__global__ __launch_bounds__(256) void sobel_kernel(const float* __restrict__ img,
                                                    float* __restrict__ out) {
    // --- XCD-chunked swizzle: nwg = 2048 = 8 XCDs x 256 ---
    const int bid = blockIdx.x;
    const int swz = (bid & 7) * 256 + (bid >> 3);    // xcd*chunk + idx
    const int bz  = swz >> 6;                        // image index (64 blocks/img)
    const int rem = swz & 63;
    const int by  = rem >> 1;                        // 32 y-bands
    const int bx  = rem & 1;                         // 2 x-halves

    const int tx = threadIdx.x;                      // 0..63 (lane)
    const int ty = threadIdx.y;                      // 0..3  (wave)
    const int x0 = bx * 256 + tx * 4;                // multiple of 4
    const int y0 = (by * 4 + ty) * 4;                // multiple of 4
    const int n  = bz;

    const float* p0 = img + (size_t)n * C * HW;
    const float* p1 = p0 + HW;
    const float* p2 = p0 + 2 * HW;

    // Row offsets (edge-pad == clamp center into [1,510] == clamp loaded rows).
    size_t ro[6];
#pragma unroll
    for (int j = 0; j < 6; ++j) {
        int row = y0 - 1 + j;
        row = min(max(row, 0), H - 1);
        ro[j] = (size_t)row * W;
    }

    // ---- prologue: issue ALL vector loads back-to-back ----
    f32x4 A[6][3];
#pragma unroll
    for (int j = 0; j < 6; ++j) {
        A[j][0] = *reinterpret_cast<const f32x4*>(p0 + ro[j] + x0);
        A[j][1] = *reinterpret_cast<const f32x4*>(p1 + ro[j] + x0);
        A[j][2] = *reinterpret_cast<const f32x4*>(p2 + ro[j] + x0);
    }

    // Block-boundary halo column (only lanes 0 and 63 load).
    const int  ecol  = (tx == 0) ? (x0 - 1) : (x0 + 4);
    const bool eneed = (tx == 0 && x0 > 0) || (tx == 63 && x0 + 4 < W);
    float e[6] = {0.f, 0.f, 0.f, 0.f, 0.f, 0.f};
    if (eneed) {
#pragma unroll
        for (int j = 0; j < 6; ++j)
            e[j] = p0[ro[j] + ecol] + p1[ro[j] + ecol] + p2[ro[j] + ecol];
    }

    float gx[4][4];
    float gy[4][4];

#pragma unroll
    for (int j = 0; j < 6; ++j) {
        const float s0 = A[j][0].x + A[j][1].x + A[j][2].x;
        const float s1 = A[j][0].y + A[j][1].y + A[j][2].y;
        const float s2 = A[j][0].z + A[j][1].z + A[j][2].z;
        const float s3 = A[j][0].w + A[j][1].w + A[j][2].w;

        float left = __shfl_up(s3, 1);
        if (tx == 0) left = e[j];          // garbage when x0==0; result discarded
        float right = __shfl_down(s0, 1);
        if (tx == 63) right = e[j];        // garbage when x0+4==W; result discarded

        const float win[6] = {left, s0, s1, s2, s3, right};

        float cd[4], cs[4];
#pragma unroll
        for (int m = 0; m < 4; ++m) {
            cd[m] = win[m] - win[m + 2];                       // Gx col weights [1,0,-1]
            cs[m] = win[m] + 2.f * win[m + 1] + win[m + 2];    // Gy col weights [1,2,1]
        }

        // Output row k (center row j=k+1) uses loaded rows k, k+1, k+2:
        //   gx[k] = cd[k] + 2*cd[k+1] + cd[k+2];  gy[k] = cs[k] - cs[k+2]
#pragma unroll
        for (int m = 0; m < 4; ++m) {
            if (j < 4)             { gx[j][m] = cd[m];       gy[j][m] = cs[m]; }
            if (j >= 1 && j <= 4)  { gx[j - 1][m] += 2.f * cd[m]; }
            if (j >= 2)            { gx[j - 2][m] += cd[m];  gy[j - 2][m] -= cs[m]; }
        }
    }

    float res[4][4];
#pragma unroll
    for (int k = 0; k < 4; ++k)
#pragma unroll
        for (int m = 0; m < 4; ++m) {
            // Tolerance is 0.75; single v_sqrt_f32 (~1 ulp) is plenty.
            res[k][m] = __builtin_amdgcn_sqrtf(gx[k][m] * gx[k][m] + gy[k][m] * gy[k][m]);
        }

    // Edge-pad fixups (result duplication). x first, then y (y copies fixed rows).
    if (x0 == 0) {
#pragma unroll
        for (int k = 0; k < 4; ++k) res[k][0] = res[k][1];
    }
    if (x0 == W - 4) {
#pragma unroll
        for (int k = 0; k < 4; ++k) res[k][3] = res[k][2];
    }
    if (y0 == 0) {
#pragma unroll
        for (int m = 0; m < 4; ++m) res[0][m] = res[1][m];
    }
    if (y0 == H - 4) {
#pragma unroll
        for (int m = 0; m < 4; ++m) res[3][m] = res[2][m];
    }

    // Streaming (non-temporal) stores: output is never re-read; keep L2 for img.
    float* o = out + (size_t)n * HW + (size_t)y0 * W + x0;
#pragma unroll
    for (int k = 0; k < 4; ++k) {
        f32x4 v = {res[k][0], res[k][1], res[k][2], res[k][3]};
        __builtin_nontemporal_store(v, reinterpret_cast<f32x4*>(o + (size_t)k * W));
    }
}

extern "C" void kernel_launch(void* const* d_in, const int* in_sizes, int n_in,
                              void* d_out, int out_size, void* d_ws, size_t ws_size,
                              hipStream_t stream) {
    const float* img = (const float*)d_in[0];
    float* out = (float*)d_out;

    dim3 block(64, 4, 1);
    dim3 grid(2048, 1, 1);   // 8 XCDs x 256-block chunks (see swizzle)
    sobel_kernel<<<grid, block, 0, stream>>>(img, out);
}